// Round 10
// baseline (907.809 us; speedup 1.0000x reference)
//
#include <hip/hip_runtime.h>

typedef unsigned short u16;
typedef u16 u16x4 __attribute__((ext_vector_type(4)));
typedef u16 u16x8 __attribute__((ext_vector_type(8)));
typedef float f32x4 __attribute__((ext_vector_type(4)));
typedef __bf16 bf16x8 __attribute__((ext_vector_type(8)));

#define NN 16384
#define EE 262144
#define DD 1024
#define DESM 1280
#define LL 5000
#define IPN 30000

static __device__ __forceinline__ u16 f2bf(float f) {
  unsigned u = __float_as_uint(f);
  u += 0x7FFF + ((u >> 16) & 1);
  return (u16)(u >> 16);
}
static __device__ __forceinline__ float bf2f(u16 h) {
  return __uint_as_float(((unsigned)h) << 16);
}

// -------- generic fp32 -> bf16 cast, optional row gather, strided dst --------
__global__ void cast_rows_k(const float* __restrict__ src, int scols,
                            const int* __restrict__ rowidx,
                            u16* __restrict__ dst, int dld, int dcol0,
                            int rows, int cols8 /* cols/8 */) {
  long total = (long)rows * cols8;
  for (long i = blockIdx.x * (long)blockDim.x + threadIdx.x; i < total;
       i += (long)gridDim.x * blockDim.x) {
    int r = (int)(i / cols8);
    int k8 = (int)(i % cols8);
    int sr = rowidx ? rowidx[r] : r;
    const f32x4* s = (const f32x4*)(src + (size_t)sr * scols + (size_t)k8 * 8);
    f32x4 a = s[0], b = s[1];
    u16x8 o;
    o[0] = f2bf(a[0]); o[1] = f2bf(a[1]); o[2] = f2bf(a[2]); o[3] = f2bf(a[3]);
    o[4] = f2bf(b[0]); o[5] = f2bf(b[1]); o[6] = f2bf(b[2]); o[7] = f2bf(b[3]);
    *(u16x8*)(dst + (size_t)r * dld + dcol0 + (size_t)k8 * 8) = o;
  }
}

// -------- EmbeddingBag(sum) over bf16 table + bias2, relu, bf16 out --------
__global__ void embed_bag_k(const u16* __restrict__ W, const int* __restrict__ idx,
                            const int* __restrict__ off, const float* __restrict__ bias2,
                            u16* __restrict__ x2b) {
  int node = blockIdx.x * 2 + (threadIdx.x >> 7);
  int t = threadIdx.x & 127;
  int beg = off[node], end = off[node + 1];
  float a[8];
#pragma unroll
  for (int j = 0; j < 8; ++j) a[j] = 0.f;
  int p = beg;
  for (; p + 8 <= end; p += 8) {
    u16x8 v[8];
#pragma unroll
    for (int q = 0; q < 8; ++q)
      v[q] = *(const u16x8*)(W + (size_t)idx[p + q] * DD + t * 8);
#pragma unroll
    for (int q = 0; q < 8; ++q)
#pragma unroll
      for (int j = 0; j < 8; ++j) a[j] += bf2f(v[q][j]);
  }
  for (; p + 2 <= end; p += 2) {
    u16x8 v0 = *(const u16x8*)(W + (size_t)idx[p] * DD + t * 8);
    u16x8 v1 = *(const u16x8*)(W + (size_t)idx[p + 1] * DD + t * 8);
#pragma unroll
    for (int j = 0; j < 8; ++j) a[j] += bf2f(v0[j]) + bf2f(v1[j]);
  }
  if (p < end) {
    u16x8 v0 = *(const u16x8*)(W + (size_t)idx[p] * DD + t * 8);
#pragma unroll
    for (int j = 0; j < 8; ++j) a[j] += bf2f(v0[j]);
  }
  f32x4 b0 = *(const f32x4*)(bias2 + t * 8);
  f32x4 b1 = *(const f32x4*)(bias2 + t * 8 + 4);
  u16x8 o;
#pragma unroll
  for (int j = 0; j < 4; ++j) o[j] = f2bf(fmaxf(a[j] + b0[j], 0.f));
#pragma unroll
  for (int j = 0; j < 4; ++j) o[j + 4] = f2bf(fmaxf(a[j + 4] + b1[j], 0.f));
  *(u16x8*)(x2b + (size_t)node * DD + t * 8) = o;
}

// -------- CSR build over dst --------
__global__ void hist_k(const int* __restrict__ dst, int* __restrict__ counts) {
  int e = blockIdx.x * blockDim.x + threadIdx.x;
  if (e < EE) atomicAdd(&counts[dst[e]], 1);
}

__global__ void scan_k(const int* __restrict__ counts, int* __restrict__ row_off) {
  __shared__ int sh[256];
  int t = threadIdx.x;
  int s = 0;
  for (int i = 0; i < 64; ++i) s += counts[t * 64 + i];
  sh[t] = s;
  __syncthreads();
  if (t == 0) {
    int run = 0;
    for (int i = 0; i < 256; ++i) { int v = sh[i]; sh[i] = run; run += v; }
    row_off[NN] = run;
  }
  __syncthreads();
  int run = sh[t];
  for (int i = 0; i < 64; ++i) { row_off[t * 64 + i] = run; run += counts[t * 64 + i]; }
}

__global__ void scatter_k(const int* __restrict__ dst, const int* __restrict__ src,
                          const float* __restrict__ selfw, const float* __restrict__ ppiw,
                          int* __restrict__ cursor, int4* __restrict__ rec) {
  int e = blockIdx.x * blockDim.x + threadIdx.x;
  if (e < EE) {
    int pos = atomicAdd(&cursor[dst[e]], 1);
    int4 r;
    r.x = src[e];
    r.y = __float_as_int(selfw[e]);
    r.z = __float_as_int(ppiw[e]);
    r.w = 0;
    rec[pos] = r;
  }
}

// -------- per-node gather aggregation: cat = [ppi_out | res] in bf16 --------
__global__ void aggregate_k(const u16* __restrict__ h, const int* __restrict__ row_off,
                            const int4* __restrict__ rec, u16* __restrict__ cat) {
  int node = blockIdx.x * 2 + (threadIdx.x >> 7);
  int t = threadIdx.x & 127;
  int beg = row_off[node], end = row_off[node + 1];
  float res[8], ppi[8];
#pragma unroll
  for (int j = 0; j < 8; ++j) { res[j] = 0.f; ppi[j] = 0.f; }
  int p = beg;
  for (; p + 8 <= end; p += 8) {
    int4 r[8];
    u16x8 m[8];
#pragma unroll
    for (int q = 0; q < 8; ++q) r[q] = rec[p + q];
#pragma unroll
    for (int q = 0; q < 8; ++q)
      m[q] = *(const u16x8*)(h + (size_t)r[q].x * DD + t * 8);
#pragma unroll
    for (int q = 0; q < 8; ++q) {
      float ws = __int_as_float(r[q].y), wp = __int_as_float(r[q].z);
#pragma unroll
      for (int j = 0; j < 8; ++j) {
        float f = bf2f(m[q][j]);
        res[j] += ws * f;
        ppi[j] += wp * f;
      }
    }
  }
  for (; p + 2 <= end; p += 2) {
    int4 r0 = rec[p], r1 = rec[p + 1];
    u16x8 m0 = *(const u16x8*)(h + (size_t)r0.x * DD + t * 8);
    u16x8 m1 = *(const u16x8*)(h + (size_t)r1.x * DD + t * 8);
    float ws0 = __int_as_float(r0.y), wp0 = __int_as_float(r0.z);
    float ws1 = __int_as_float(r1.y), wp1 = __int_as_float(r1.z);
#pragma unroll
    for (int j = 0; j < 8; ++j) {
      float f0 = bf2f(m0[j]), f1 = bf2f(m1[j]);
      res[j] += ws0 * f0 + ws1 * f1;
      ppi[j] += wp0 * f0 + wp1 * f1;
    }
  }
  if (p < end) {
    int4 r0 = rec[p];
    u16x8 m0 = *(const u16x8*)(h + (size_t)r0.x * DD + t * 8);
    float ws = __int_as_float(r0.y), wp = __int_as_float(r0.z);
#pragma unroll
    for (int j = 0; j < 8; ++j) {
      float f = bf2f(m0[j]);
      res[j] += ws * f;
      ppi[j] += wp * f;
    }
  }
  u16x8 o0, o1;
#pragma unroll
  for (int j = 0; j < 8; ++j) { o0[j] = f2bf(ppi[j]); o1[j] = f2bf(res[j]); }
  *(u16x8*)(cat + (size_t)node * 2048 + t * 8) = o0;
  *(u16x8*)(cat + (size_t)node * 2048 + DD + t * 8) = o1;
}

// ======== 256x256x64 8-wave fully-pipelined GEMM — ROW-SPLIT LDS halves ========
// Round-9 verified structure (355us, MfmaUtil 48.5, conflicts 0).
// Round-10 change: within-XCD-chunk BANDED-SERPENTINE tile order for wide grids
// (gx>=8, i.e. the final GEMM).  ~64 blocks run concurrently per XCD; row-major
// order makes them span all 20 B panels (23.6 MB live vs 4 MB L2) -> B thrash
// (round-6/9 FETCH ~ 2A+19B).  Col-major streams 75 MB of A per XCD (round 8,
// worse).  Banded: chunk = 8 rows x 20 cols; iterate width-2 col bands,
// serpentine rows.  Concurrent live set = chunk's 8 A panels (shared by all
// bands) + ~8 B panels, B reuse distance 2 blocks.  L2-fill traffic drops
// ~1.6 GB -> ~0.9 GB; B HBM refetch should follow.
static __device__ __forceinline__ void stage_half(const char* Gb, size_t ldb, int rowbase,
                                                  int rowmax, int kbyte, char* lds_dest_wb,
                                                  int s_rowoff, int s_inner) {
#pragma unroll
  for (int j = 0; j < 2; ++j) {
    int row = rowbase + j * 64 + s_rowoff;
    if (row > rowmax) row = rowmax;
    const char* src = Gb + (size_t)row * ldb + kbyte + s_inner;
    __builtin_amdgcn_global_load_lds(
        (const __attribute__((address_space(1))) void*)src,
        (__attribute__((address_space(3))) void*)(lds_dest_wb + j * 8192), 16, 0, 0);
  }
}

static __device__ __forceinline__ bf16x8 ldr2(const char* base, int row, int kk, int slot) {
  unsigned g = ((unsigned)(kk * 4 + slot)) ^ ((unsigned)row & 7u);
  return *(const bf16x8*)(base + (unsigned)row * 128u + g * 16u);
}

// MODE 0: h = bf16(sm0*relu(acc+bias0+bias1) + sm1*x2b)  (x2b pre-relu'd bf16)
// MODE 1: bf16(relu(acc + bias0))
// MODE 2: acc + bias0, fp32 out, col-guard vs N
template <int MODE>
__global__ __launch_bounds__(512, 2) void gemm8_k(
    const u16* __restrict__ A, const u16* __restrict__ B, int M, int N, int K,
    void* __restrict__ Cout, int ldc, const float* __restrict__ bias0,
    const float* __restrict__ bias1, const u16* __restrict__ x2b,
    const float* __restrict__ wmix) {
  __shared__ char lds[131072];
  char* ldsA = lds;            // [2][256][128B]
  char* ldsB = lds + 65536;
  const int tid = threadIdx.x;
  const int lane = tid & 63;
  const int wid = tid >> 6;
  const int wr = wid >> 2;
  const int wc = wid & 3;
  // bijective XCD chunk swizzle (contiguous swz range per XCD)
  const int nwg = gridDim.x * gridDim.y;
  const int flat = blockIdx.x + gridDim.x * blockIdx.y;
  const int swz = (flat & 7) * (nwg >> 3) + (flat >> 3);
  int row0, col0;
  {
    const int gx = gridDim.x, gy = gridDim.y;
    if (gx >= 8) {
      // within-chunk banded serpentine (W=2)
      const int CHUNK = nwg >> 3;       // blocks per XCD chunk
      const int CR = CHUNK / gx;        // chunk rows (8 for final GEMM)
      int chunk = swz / CHUNK;
      int w = swz - chunk * CHUNK;
      const int bandsz = CR * 2;
      int band = w / bandsz;
      int rem = w - band * bandsz;
      int r = rem >> 1;
      int cinb = rem & 1;
      if (band & 1) r = CR - 1 - r;
      row0 = (chunk * CR + r) * 256;
      col0 = (band * 2 + cinb) * 256;
    } else {
      row0 = (swz / gx) * 256;
      col0 = (swz % gx) * 256;
    }
    (void)gy;
  }
  const int NT = K >> 6;
  const size_t lda = (size_t)K * 2;
  const char* Ab = (const char*)A;
  const char* Bb = (const char*)B;
  const int l15 = lane & 15;
  const int slot = lane >> 4;
  const int s_rowoff = wid * 8 + (lane >> 3);
  const int s_inner = (((lane & 7) ^ ((lane >> 3) & 7)) << 4);
  const int wb = wid * 1024;

  f32x4 acc[8][4];
#pragma unroll
  for (int m = 0; m < 8; ++m)
#pragma unroll
    for (int n = 0; n < 4; ++n) acc[m][n] = (f32x4){0.f, 0.f, 0.f, 0.f};

  // prologue: tile0 {Blo,Bhi,Alo,Ahi} + tile1 {Blo,Bhi,Alo}; Ahi(1) comes at P1(0)
  const int k1 = (NT > 1) ? 128 : 0;
  stage_half(Bb, lda, col0,       N - 1, 0,  ldsB + 0     + wb, s_rowoff, s_inner);
  stage_half(Bb, lda, col0 + 128, N - 1, 0,  ldsB + 16384 + wb, s_rowoff, s_inner);
  stage_half(Ab, lda, row0,       M - 1, 0,  ldsA + 0     + wb, s_rowoff, s_inner);
  stage_half(Ab, lda, row0 + 128, M - 1, 0,  ldsA + 16384 + wb, s_rowoff, s_inner);
  stage_half(Bb, lda, col0,       N - 1, k1, ldsB + 32768 + wb, s_rowoff, s_inner);
  stage_half(Bb, lda, col0 + 128, N - 1, k1, ldsB + 49152 + wb, s_rowoff, s_inner);
  stage_half(Ab, lda, row0,       M - 1, k1, ldsA + 32768 + wb, s_rowoff, s_inner);
  asm volatile("s_waitcnt vmcnt(6)" ::: "memory");  // tile-0 fully landed
  __builtin_amdgcn_s_barrier();

  bf16x8 afP[4], afQ[4], bqP[4], bqQ[4];
#pragma unroll
  for (int m = 0; m < 4; ++m) afP[m] = ldr2(ldsA, wr * 128 + m * 16 + l15, 0, slot);
#pragma unroll
  for (int n = 0; n < 4; ++n) bqP[n] = ldr2(ldsB, wc * 64 + n * 16 + l15, 0, slot);

  for (int t = 0; t < NT; ++t) {
    const int d = t & 1;
    char* Ad = ldsA + d * 32768;
    char* Bd = ldsB + d * 32768;
    char* AdN = ldsA + (d ^ 1) * 32768;
    char* BdN = ldsB + (d ^ 1) * 32768;
    const int ts1 = (t + 1 < NT) ? t + 1 : NT - 1;
    const int ts2 = (t + 2 < NT) ? t + 2 : NT - 1;

    // ---- P1: read afQ=A-mhi-kk0(t), bqQ=B-kk1(t); stage Ahi(t+1); MFMA mlo*kk0
#pragma unroll
    for (int m = 0; m < 4; ++m) afQ[m] = ldr2(Ad, wr * 128 + (m + 4) * 16 + l15, 0, slot);
#pragma unroll
    for (int n = 0; n < 4; ++n) bqQ[n] = ldr2(Bd, wc * 64 + n * 16 + l15, 1, slot);
    stage_half(Ab, lda, row0 + 128, M - 1, ts1 * 128,
               ldsA + ((t + 1) & 1) * 32768 + 16384 + wb, s_rowoff, s_inner);
    __builtin_amdgcn_sched_barrier(0);
    __builtin_amdgcn_s_setprio(1);
#pragma unroll
    for (int m = 0; m < 4; ++m)
#pragma unroll
      for (int n = 0; n < 4; ++n)
        acc[m][n] = __builtin_amdgcn_mfma_f32_16x16x32_bf16(afP[m], bqP[n], acc[m][n], 0, 0, 0);
    __builtin_amdgcn_s_setprio(0);
    __builtin_amdgcn_s_barrier();

    // ---- P2: read afP=A-mhi-kk1(t); stage Blo(t+2); MFMA mhi*kk0
#pragma unroll
    for (int m = 0; m < 4; ++m) afP[m] = ldr2(Ad, wr * 128 + (m + 4) * 16 + l15, 1, slot);
    stage_half(Bb, lda, col0, N - 1, ts2 * 128, Bd + wb, s_rowoff, s_inner);
    __builtin_amdgcn_sched_barrier(0);
    __builtin_amdgcn_s_setprio(1);
#pragma unroll
    for (int m = 0; m < 4; ++m)
#pragma unroll
      for (int n = 0; n < 4; ++n)
        acc[m + 4][n] = __builtin_amdgcn_mfma_f32_16x16x32_bf16(afQ[m], bqP[n], acc[m + 4][n], 0, 0, 0);
    __builtin_amdgcn_s_setprio(0);
    __builtin_amdgcn_s_barrier();

    // ---- P3: read afQ=A-mlo-kk1(t); stage Bhi(t+2); MFMA mhi*kk1; vmcnt(4)
#pragma unroll
    for (int m = 0; m < 4; ++m) afQ[m] = ldr2(Ad, wr * 128 + m * 16 + l15, 1, slot);
    stage_half(Bb, lda, col0 + 128, N - 1, ts2 * 128, Bd + 16384 + wb, s_rowoff, s_inner);
    __builtin_amdgcn_sched_barrier(0);
    __builtin_amdgcn_s_setprio(1);
#pragma unroll
    for (int m = 0; m < 4; ++m)
#pragma unroll
      for (int n = 0; n < 4; ++n)
        acc[m + 4][n] = __builtin_amdgcn_mfma_f32_16x16x32_bf16(afP[m], bqQ[n], acc[m + 4][n], 0, 0, 0);
    __builtin_amdgcn_s_setprio(0);
    asm volatile("s_waitcnt vmcnt(4)" ::: "memory");
    __builtin_amdgcn_s_barrier();

    // ---- P4: read afP=A-mlo-kk0(t+1), bqP=B-kk0(t+1); stage Alo(t+2); MFMA mlo*kk1
#pragma unroll
    for (int m = 0; m < 4; ++m) afP[m] = ldr2(AdN, wr * 128 + m * 16 + l15, 0, slot);
#pragma unroll
    for (int n = 0; n < 4; ++n) bqP[n] = ldr2(BdN, wc * 64 + n * 16 + l15, 0, slot);
    stage_half(Ab, lda, row0, M - 1, ts2 * 128, Ad + wb, s_rowoff, s_inner);
    __builtin_amdgcn_sched_barrier(0);
    __builtin_amdgcn_s_setprio(1);
#pragma unroll
    for (int m = 0; m < 4; ++m)
#pragma unroll
      for (int n = 0; n < 4; ++n)
        acc[m][n] = __builtin_amdgcn_mfma_f32_16x16x32_bf16(afQ[m], bqQ[n], acc[m][n], 0, 0, 0);
    __builtin_amdgcn_s_setprio(0);
    __builtin_amdgcn_s_barrier();
  }

  float sm0 = 0.f, sm1 = 0.f;
  if (MODE == 0) {
    float w0 = wmix[0], w1 = wmix[1];
    float mx = fmaxf(w0, w1);
    float e0 = expf(w0 - mx), e1 = expf(w1 - mx);
    float inv = 1.f / (e0 + e1);
    sm0 = e0 * inv;
    sm1 = e1 * inv;
  }
  float bc[4];
  int cs[4];
#pragma unroll
  for (int n = 0; n < 4; ++n) {
    int c = col0 + wc * 64 + n * 16 + l15;
    cs[n] = c;
    bc[n] = (MODE == 2 && c >= N) ? 0.f : (bias0[c] + (MODE == 0 ? bias1[c] : 0.f));
  }
#pragma unroll
  for (int m = 0; m < 8; ++m) {
#pragma unroll
    for (int n = 0; n < 4; ++n) {
      int c = cs[n];
      if (MODE == 2 && c >= N) continue;
      int r0 = row0 + wr * 128 + m * 16 + slot * 4;
#pragma unroll
      for (int r = 0; r < 4; ++r) {
        float v = acc[m][n][r] + bc[n];
        int rr = r0 + r;
        if (MODE == 0) {
          float x1v = fmaxf(v, 0.f);
          float x2v = bf2f(x2b[(size_t)rr * DD + c]);
          ((u16*)Cout)[(size_t)rr * ldc + c] = f2bf(sm0 * x1v + sm1 * x2v);
        } else if (MODE == 1) {
          ((u16*)Cout)[(size_t)rr * ldc + c] = f2bf(fmaxf(v, 0.f));
        } else {
          ((float*)Cout)[(size_t)rr * ldc + c] = v;
        }
      }
    }
  }
}

extern "C" void kernel_launch(void* const* d_in, const int* in_sizes, int n_in,
                              void* d_out, int out_size, void* d_ws, size_t ws_size,
                              hipStream_t stream) {
  const float* esm   = (const float*)d_in[0];
  const float* ipw   = (const float*)d_in[1];
  const float* Wesm  = (const float*)d_in[2];
  const float* besm  = (const float*)d_in[3];
  const float* bias1 = (const float*)d_in[4];
  const float* bias2 = (const float*)d_in[5];
  const float* wmix  = (const float*)d_in[6];
  const float* Wupd  = (const float*)d_in[7];
  const float* bupd  = (const float*)d_in[8];
  const float* Wout  = (const float*)d_in[9];
  const float* bout  = (const float*)d_in[10];
  const float* selfw = (const float*)d_in[11];
  const float* ppiw  = (const float*)d_in[12];
  const int* inputs  = (const int*)d_in[13];
  const int* ipidx   = (const int*)d_in[14];
  const int* ipoff   = (const int*)d_in[15];
  const int* src     = (const int*)d_in[16];
  const int* dst     = (const int*)d_in[17];
  const int* tgt     = (const int*)d_in[18];
  float* out = (float*)d_out;

  char* ws = (char*)d_ws;
  size_t o = 0;
  auto take = [&](size_t b) {
    char* r = ws + o;
    o += (b + 255) & ~(size_t)255;
    return r;
  };
  u16* Wesm_b = (u16*)take(1024ull * 1280 * 2);
  u16* Wupd_b = (u16*)take(2ull * 1024 * 2048 * 2);
  u16* Wout_b = (u16*)take(5000ull * 2304 * 2);
  int* counts  = (int*)take((size_t)NN * 4);
  int* row_off = (int*)take((size_t)(NN + 1) * 4);
  int* cursor  = (int*)take((size_t)NN * 4);
  int4* rec    = (int4*)take((size_t)EE * 16);
  u16* h_b     = (u16*)take((size_t)NN * DD * 2);
  char* shared0 = ws + o;
  size_t x2_b = ((size_t)NN * DD * 2 + 255) & ~(size_t)255;
  size_t a1_b = ((size_t)NN * DESM * 2 + 255) & ~(size_t)255;
  u16* x2b    = (u16*)shared0;
  u16* A1     = (u16*)(shared0 + x2_b);
  u16* ipw_b  = (u16*)(shared0 + x2_b + a1_b);
  u16* cat_b  = (u16*)shared0;
  u16* A_last = (u16*)(shared0 + x2_b + a1_b);

  // ---- weight casts to bf16 ----
  cast_rows_k<<<2048, 256, 0, stream>>>(Wesm, 1280, nullptr, Wesm_b, 1280, 0, 1024, 160);
  cast_rows_k<<<2048, 256, 0, stream>>>(Wupd, 2048, nullptr, Wupd_b, 2048, 0, 2048, 256);
  cast_rows_k<<<2048, 256, 0, stream>>>(Wout, 2304, nullptr, Wout_b, 2304, 0, 5000, 288);
  cast_rows_k<<<4096, 256, 0, stream>>>(ipw, 1024, nullptr, ipw_b, 1024, 0, IPN, 128);

  // ---- x2 = relu(bag + bias2) as bf16 ----
  embed_bag_k<<<NN / 2, 256, 0, stream>>>(ipw_b, ipidx, ipoff, bias2, x2b);

  // ---- gather ESM rows for x1 GEMM ----
  cast_rows_k<<<4096, 256, 0, stream>>>(esm, 1280, inputs, A1, 1280, 0, NN, 160);

  // ---- CSR by dst with packed edge records ----
  hipMemsetAsync(counts, 0, (size_t)NN * 4, stream);
  hist_k<<<EE / 256, 256, 0, stream>>>(dst, counts);
  scan_k<<<1, 256, 0, stream>>>(counts, row_off);
  hipMemcpyAsync(cursor, row_off, (size_t)NN * 4, hipMemcpyDeviceToDevice, stream);
  scatter_k<<<EE / 256, 256, 0, stream>>>(dst, src, selfw, ppiw, cursor, rec);

  // ---- x1 GEMM fused with softmax-mix of x2 -> h (bf16) ----
  gemm8_k<0><<<dim3(4, 64), 512, 0, stream>>>(A1, Wesm_b, NN, 1024, 1280, h_b, 1024,
                                              besm, bias1, x2b, wmix);

  // ---- ESM gather for the final concat ----
  cast_rows_k<<<4096, 256, 0, stream>>>(esm, 1280, tgt, A_last, 2304, 1024, NN, 160);

  // ---- GCN layer 0 ----
  aggregate_k<<<NN / 2, 256, 0, stream>>>(h_b, row_off, rec, cat_b);
  gemm8_k<1><<<dim3(4, 64), 512, 0, stream>>>(cat_b, Wupd_b, NN, 1024, 2048, h_b, 1024,
                                              bupd, nullptr, nullptr, nullptr);

  // ---- GCN layer 1 ----
  aggregate_k<<<NN / 2, 256, 0, stream>>>(h_b, row_off, rec, cat_b);
  gemm8_k<1><<<dim3(4, 64), 512, 0, stream>>>(cat_b, Wupd_b + (size_t)1024 * 2048, NN, 1024,
                                              2048, A_last, 2304, bupd + 1024, nullptr,
                                              nullptr, nullptr);

  // ---- final output GEMM [16384,2304] x [5000,2304]^T ----
  gemm8_k<2><<<dim3(20, 64), 512, 0, stream>>>(A_last, Wout_b, NN, 5000, 2304, out, 5000,
                                               bout, nullptr, nullptr, nullptr);
}

// Round 11
// 893.388 us; speedup vs baseline: 1.0161x; 1.0161x over previous
//
#include <hip/hip_runtime.h>

typedef unsigned short u16;
typedef u16 u16x4 __attribute__((ext_vector_type(4)));
typedef u16 u16x8 __attribute__((ext_vector_type(8)));
typedef float f32x4 __attribute__((ext_vector_type(4)));
typedef __bf16 bf16x8 __attribute__((ext_vector_type(8)));

#define NN 16384
#define EE 262144
#define DD 1024
#define DESM 1280
#define LL 5000
#define IPN 30000

static __device__ __forceinline__ u16 f2bf(float f) {
  unsigned u = __float_as_uint(f);
  u += 0x7FFF + ((u >> 16) & 1);
  return (u16)(u >> 16);
}
static __device__ __forceinline__ float bf2f(u16 h) {
  return __uint_as_float(((unsigned)h) << 16);
}

// -------- fp32 -> bf16 cast, optional row gather; 2D grid (y=row) — no div --------
__global__ void cast_rows_k(const float* __restrict__ src, int scols,
                            const int* __restrict__ rowidx,
                            u16* __restrict__ dst, int dld, int dcol0,
                            int cols8 /* cols/8 */) {
  int r = blockIdx.y;
  int k8 = blockIdx.x * blockDim.x + threadIdx.x;
  if (k8 >= cols8) return;
  int sr = rowidx ? rowidx[r] : r;
  const f32x4* s = (const f32x4*)(src + (size_t)sr * scols + (size_t)k8 * 8);
  f32x4 a = s[0], b = s[1];
  u16x8 o;
  o[0] = f2bf(a[0]); o[1] = f2bf(a[1]); o[2] = f2bf(a[2]); o[3] = f2bf(a[3]);
  o[4] = f2bf(b[0]); o[5] = f2bf(b[1]); o[6] = f2bf(b[2]); o[7] = f2bf(b[3]);
  *(u16x8*)(dst + (size_t)r * dld + dcol0 + (size_t)k8 * 8) = o;
}

// -------- EmbeddingBag(sum) over bf16 table + bias2, relu, bf16 out --------
__global__ void embed_bag_k(const u16* __restrict__ W, const int* __restrict__ idx,
                            const int* __restrict__ off, const float* __restrict__ bias2,
                            u16* __restrict__ x2b) {
  int node = blockIdx.x * 2 + (threadIdx.x >> 7);
  int t = threadIdx.x & 127;
  int beg = off[node], end = off[node + 1];
  float a[8];
#pragma unroll
  for (int j = 0; j < 8; ++j) a[j] = 0.f;
  int p = beg;
  for (; p + 8 <= end; p += 8) {
    u16x8 v[8];
#pragma unroll
    for (int q = 0; q < 8; ++q)
      v[q] = *(const u16x8*)(W + (size_t)idx[p + q] * DD + t * 8);
#pragma unroll
    for (int q = 0; q < 8; ++q)
#pragma unroll
      for (int j = 0; j < 8; ++j) a[j] += bf2f(v[q][j]);
  }
  for (; p + 2 <= end; p += 2) {
    u16x8 v0 = *(const u16x8*)(W + (size_t)idx[p] * DD + t * 8);
    u16x8 v1 = *(const u16x8*)(W + (size_t)idx[p + 1] * DD + t * 8);
#pragma unroll
    for (int j = 0; j < 8; ++j) a[j] += bf2f(v0[j]) + bf2f(v1[j]);
  }
  if (p < end) {
    u16x8 v0 = *(const u16x8*)(W + (size_t)idx[p] * DD + t * 8);
#pragma unroll
    for (int j = 0; j < 8; ++j) a[j] += bf2f(v0[j]);
  }
  f32x4 b0 = *(const f32x4*)(bias2 + t * 8);
  f32x4 b1 = *(const f32x4*)(bias2 + t * 8 + 4);
  u16x8 o;
#pragma unroll
  for (int j = 0; j < 4; ++j) o[j] = f2bf(fmaxf(a[j] + b0[j], 0.f));
#pragma unroll
  for (int j = 0; j < 4; ++j) o[j + 4] = f2bf(fmaxf(a[j + 4] + b1[j], 0.f));
  *(u16x8*)(x2b + (size_t)node * DD + t * 8) = o;
}

// -------- CSR build over dst --------
__global__ void hist_k(const int* __restrict__ dst, int* __restrict__ counts) {
  int e = blockIdx.x * blockDim.x + threadIdx.x;
  if (e < EE) atomicAdd(&counts[dst[e]], 1);
}

__global__ void scan_k(const int* __restrict__ counts, int* __restrict__ row_off) {
  __shared__ int sh[256];
  int t = threadIdx.x;
  int s = 0;
  for (int i = 0; i < 64; ++i) s += counts[t * 64 + i];
  sh[t] = s;
  __syncthreads();
  if (t == 0) {
    int run = 0;
    for (int i = 0; i < 256; ++i) { int v = sh[i]; sh[i] = run; run += v; }
    row_off[NN] = run;
  }
  __syncthreads();
  int run = sh[t];
  for (int i = 0; i < 64; ++i) { row_off[t * 64 + i] = run; run += counts[t * 64 + i]; }
}

__global__ void scatter_k(const int* __restrict__ dst, const int* __restrict__ src,
                          const float* __restrict__ selfw, const float* __restrict__ ppiw,
                          int* __restrict__ cursor, int4* __restrict__ rec) {
  int e = blockIdx.x * blockDim.x + threadIdx.x;
  if (e < EE) {
    int pos = atomicAdd(&cursor[dst[e]], 1);
    int4 r;
    r.x = src[e];
    r.y = __float_as_int(selfw[e]);
    r.z = __float_as_int(ppiw[e]);
    r.w = 0;
    rec[pos] = r;
  }
}

// -------- per-node gather aggregation: cat = [ppi_out | res] in bf16 --------
__global__ void aggregate_k(const u16* __restrict__ h, const int* __restrict__ row_off,
                            const int4* __restrict__ rec, u16* __restrict__ cat) {
  int node = blockIdx.x * 2 + (threadIdx.x >> 7);
  int t = threadIdx.x & 127;
  int beg = row_off[node], end = row_off[node + 1];
  float res[8], ppi[8];
#pragma unroll
  for (int j = 0; j < 8; ++j) { res[j] = 0.f; ppi[j] = 0.f; }
  int p = beg;
  for (; p + 8 <= end; p += 8) {
    int4 r[8];
    u16x8 m[8];
#pragma unroll
    for (int q = 0; q < 8; ++q) r[q] = rec[p + q];
#pragma unroll
    for (int q = 0; q < 8; ++q)
      m[q] = *(const u16x8*)(h + (size_t)r[q].x * DD + t * 8);
#pragma unroll
    for (int q = 0; q < 8; ++q) {
      float ws = __int_as_float(r[q].y), wp = __int_as_float(r[q].z);
#pragma unroll
      for (int j = 0; j < 8; ++j) {
        float f = bf2f(m[q][j]);
        res[j] += ws * f;
        ppi[j] += wp * f;
      }
    }
  }
  for (; p + 2 <= end; p += 2) {
    int4 r0 = rec[p], r1 = rec[p + 1];
    u16x8 m0 = *(const u16x8*)(h + (size_t)r0.x * DD + t * 8);
    u16x8 m1 = *(const u16x8*)(h + (size_t)r1.x * DD + t * 8);
    float ws0 = __int_as_float(r0.y), wp0 = __int_as_float(r0.z);
    float ws1 = __int_as_float(r1.y), wp1 = __int_as_float(r1.z);
#pragma unroll
    for (int j = 0; j < 8; ++j) {
      float f0 = bf2f(m0[j]), f1 = bf2f(m1[j]);
      res[j] += ws0 * f0 + ws1 * f1;
      ppi[j] += wp0 * f0 + wp1 * f1;
    }
  }
  if (p < end) {
    int4 r0 = rec[p];
    u16x8 m0 = *(const u16x8*)(h + (size_t)r0.x * DD + t * 8);
    float ws = __int_as_float(r0.y), wp = __int_as_float(r0.z);
#pragma unroll
    for (int j = 0; j < 8; ++j) {
      float f = bf2f(m0[j]);
      res[j] += ws * f;
      ppi[j] += wp * f;
    }
  }
  u16x8 o0, o1;
#pragma unroll
  for (int j = 0; j < 8; ++j) { o0[j] = f2bf(ppi[j]); o1[j] = f2bf(res[j]); }
  *(u16x8*)(cat + (size_t)node * 2048 + t * 8) = o0;
  *(u16x8*)(cat + (size_t)node * 2048 + DD + t * 8) = o1;
}

// ======== 256x256x64 8-wave GEMM — row-split LDS, TWO barriers per K-tile ========
// Round-11 change: removed the end-P2 and end-P4 barriers.  WAR audit: window
// {P2,P3} stages only B-buffer halves while reading only A-buffer (disjoint);
// window {P4(t),P1(t+1)} reads only buffer d^1 while staging only buffer d
// (disjoint).  Load-bearing barriers: end-P1 (P1's B-kk1 reads vs P2's Blo
// stage) and end-P3 (vmcnt(4) anchor).  vmcnt ledger re-audited at 2 barriers:
// outstanding 12 -> wait 4 at each BAR2 completes ALL of tile t+1 before its
// first read at P4(t); pipeline never drains.  Round-10 cycle accounting:
// wall 4627 cy/tile vs MFMA 2065 + LDS ~2800 (overlappable) -> ~1700 cy of
// barrier bubbles; halving barrier count targets that.
static __device__ __forceinline__ void stage_half(const char* Gb, size_t ldb, int rowbase,
                                                  int rowmax, int kbyte, char* lds_dest_wb,
                                                  int s_rowoff, int s_inner) {
#pragma unroll
  for (int j = 0; j < 2; ++j) {
    int row = rowbase + j * 64 + s_rowoff;
    if (row > rowmax) row = rowmax;
    const char* src = Gb + (size_t)row * ldb + kbyte + s_inner;
    __builtin_amdgcn_global_load_lds(
        (const __attribute__((address_space(1))) void*)src,
        (__attribute__((address_space(3))) void*)(lds_dest_wb + j * 8192), 16, 0, 0);
  }
}

static __device__ __forceinline__ bf16x8 ldr2(const char* base, int row, int kk, int slot) {
  unsigned g = ((unsigned)(kk * 4 + slot)) ^ ((unsigned)row & 7u);
  return *(const bf16x8*)(base + (unsigned)row * 128u + g * 16u);
}

// MODE 0: h = bf16(sm0*relu(acc+bias0+bias1) + sm1*x2b)  (x2b pre-relu'd bf16)
// MODE 1: bf16(relu(acc + bias0))
// MODE 2: acc + bias0, fp32 out, col-guard vs N
template <int MODE>
__global__ __launch_bounds__(512, 2) void gemm8_k(
    const u16* __restrict__ A, const u16* __restrict__ B, int M, int N, int K,
    void* __restrict__ Cout, int ldc, const float* __restrict__ bias0,
    const float* __restrict__ bias1, const u16* __restrict__ x2b,
    const float* __restrict__ wmix) {
  __shared__ char lds[131072];
  char* ldsA = lds;            // [2][256][128B]
  char* ldsB = lds + 65536;
  const int tid = threadIdx.x;
  const int lane = tid & 63;
  const int wid = tid >> 6;
  const int wr = wid >> 2;
  const int wc = wid & 3;
  // bijective XCD chunk swizzle; banded-serpentine within chunk for wide grids
  const int nwg = gridDim.x * gridDim.y;
  const int flat = blockIdx.x + gridDim.x * blockIdx.y;
  const int swz = (flat & 7) * (nwg >> 3) + (flat >> 3);
  int row0, col0;
  {
    const int gx = gridDim.x;
    if (gx >= 8) {
      const int CHUNK = nwg >> 3;
      const int CR = CHUNK / gx;
      int chunk = swz / CHUNK;
      int w = swz - chunk * CHUNK;
      const int bandsz = CR * 2;
      int band = w / bandsz;
      int rem = w - band * bandsz;
      int r = rem >> 1;
      int cinb = rem & 1;
      if (band & 1) r = CR - 1 - r;
      row0 = (chunk * CR + r) * 256;
      col0 = (band * 2 + cinb) * 256;
    } else {
      row0 = (swz / gx) * 256;
      col0 = (swz % gx) * 256;
    }
  }
  const int NT = K >> 6;
  const size_t lda = (size_t)K * 2;
  const char* Ab = (const char*)A;
  const char* Bb = (const char*)B;
  const int l15 = lane & 15;
  const int slot = lane >> 4;
  const int s_rowoff = wid * 8 + (lane >> 3);
  const int s_inner = (((lane & 7) ^ ((lane >> 3) & 7)) << 4);
  const int wb = wid * 1024;

  f32x4 acc[8][4];
#pragma unroll
  for (int m = 0; m < 8; ++m)
#pragma unroll
    for (int n = 0; n < 4; ++n) acc[m][n] = (f32x4){0.f, 0.f, 0.f, 0.f};

  // prologue: tile0 {Blo,Bhi,Alo,Ahi} + tile1 {Blo,Bhi,Alo}; Ahi(1) comes at P1(0)
  const int k1 = (NT > 1) ? 128 : 0;
  stage_half(Bb, lda, col0,       N - 1, 0,  ldsB + 0     + wb, s_rowoff, s_inner);
  stage_half(Bb, lda, col0 + 128, N - 1, 0,  ldsB + 16384 + wb, s_rowoff, s_inner);
  stage_half(Ab, lda, row0,       M - 1, 0,  ldsA + 0     + wb, s_rowoff, s_inner);
  stage_half(Ab, lda, row0 + 128, M - 1, 0,  ldsA + 16384 + wb, s_rowoff, s_inner);
  stage_half(Bb, lda, col0,       N - 1, k1, ldsB + 32768 + wb, s_rowoff, s_inner);
  stage_half(Bb, lda, col0 + 128, N - 1, k1, ldsB + 49152 + wb, s_rowoff, s_inner);
  stage_half(Ab, lda, row0,       M - 1, k1, ldsA + 32768 + wb, s_rowoff, s_inner);
  asm volatile("s_waitcnt vmcnt(6)" ::: "memory");  // tile-0 fully landed
  __builtin_amdgcn_s_barrier();

  bf16x8 afP[4], afQ[4], bqP[4], bqQ[4];
#pragma unroll
  for (int m = 0; m < 4; ++m) afP[m] = ldr2(ldsA, wr * 128 + m * 16 + l15, 0, slot);
#pragma unroll
  for (int n = 0; n < 4; ++n) bqP[n] = ldr2(ldsB, wc * 64 + n * 16 + l15, 0, slot);

  for (int t = 0; t < NT; ++t) {
    const int d = t & 1;
    char* Ad = ldsA + d * 32768;
    char* Bd = ldsB + d * 32768;
    char* AdN = ldsA + (d ^ 1) * 32768;
    char* BdN = ldsB + (d ^ 1) * 32768;
    const int ts1 = (t + 1 < NT) ? t + 1 : NT - 1;
    const int ts2 = (t + 2 < NT) ? t + 2 : NT - 1;

    // ---- P1: read afQ=A-mhi-kk0(t), bqQ=B-kk1(t); stage Ahi(t+1); MFMA mlo*kk0; BAR
#pragma unroll
    for (int m = 0; m < 4; ++m) afQ[m] = ldr2(Ad, wr * 128 + (m + 4) * 16 + l15, 0, slot);
#pragma unroll
    for (int n = 0; n < 4; ++n) bqQ[n] = ldr2(Bd, wc * 64 + n * 16 + l15, 1, slot);
    stage_half(Ab, lda, row0 + 128, M - 1, ts1 * 128,
               ldsA + ((t + 1) & 1) * 32768 + 16384 + wb, s_rowoff, s_inner);
    __builtin_amdgcn_sched_barrier(0);
    __builtin_amdgcn_s_setprio(1);
#pragma unroll
    for (int m = 0; m < 4; ++m)
#pragma unroll
      for (int n = 0; n < 4; ++n)
        acc[m][n] = __builtin_amdgcn_mfma_f32_16x16x32_bf16(afP[m], bqP[n], acc[m][n], 0, 0, 0);
    __builtin_amdgcn_s_setprio(0);
    __builtin_amdgcn_s_barrier();

    // ---- P2: read afP=A-mhi-kk1(t); stage Blo(t+2); MFMA mhi*kk0  (no barrier)
#pragma unroll
    for (int m = 0; m < 4; ++m) afP[m] = ldr2(Ad, wr * 128 + (m + 4) * 16 + l15, 1, slot);
    stage_half(Bb, lda, col0, N - 1, ts2 * 128, Bd + wb, s_rowoff, s_inner);
    __builtin_amdgcn_sched_barrier(0);
    __builtin_amdgcn_s_setprio(1);
#pragma unroll
    for (int m = 0; m < 4; ++m)
#pragma unroll
      for (int n = 0; n < 4; ++n)
        acc[m + 4][n] = __builtin_amdgcn_mfma_f32_16x16x32_bf16(afQ[m], bqP[n], acc[m + 4][n], 0, 0, 0);
    __builtin_amdgcn_s_setprio(0);

    // ---- P3: read afQ=A-mlo-kk1(t); stage Bhi(t+2); MFMA mhi*kk1; vmcnt(4); BAR
#pragma unroll
    for (int m = 0; m < 4; ++m) afQ[m] = ldr2(Ad, wr * 128 + m * 16 + l15, 1, slot);
    stage_half(Bb, lda, col0 + 128, N - 1, ts2 * 128, Bd + 16384 + wb, s_rowoff, s_inner);
    __builtin_amdgcn_sched_barrier(0);
    __builtin_amdgcn_s_setprio(1);
#pragma unroll
    for (int m = 0; m < 4; ++m)
#pragma unroll
      for (int n = 0; n < 4; ++n)
        acc[m + 4][n] = __builtin_amdgcn_mfma_f32_16x16x32_bf16(afP[m], bqQ[n], acc[m + 4][n], 0, 0, 0);
    __builtin_amdgcn_s_setprio(0);
    asm volatile("s_waitcnt vmcnt(4)" ::: "memory");
    __builtin_amdgcn_s_barrier();

    // ---- P4: read afP=A-mlo-kk0(t+1), bqP=B-kk0(t+1); stage Alo(t+2); MFMA mlo*kk1
#pragma unroll
    for (int m = 0; m < 4; ++m) afP[m] = ldr2(AdN, wr * 128 + m * 16 + l15, 0, slot);
#pragma unroll
    for (int n = 0; n < 4; ++n) bqP[n] = ldr2(BdN, wc * 64 + n * 16 + l15, 0, slot);
    stage_half(Ab, lda, row0, M - 1, ts2 * 128, Ad + wb, s_rowoff, s_inner);
    __builtin_amdgcn_sched_barrier(0);
    __builtin_amdgcn_s_setprio(1);
#pragma unroll
    for (int m = 0; m < 4; ++m)
#pragma unroll
      for (int n = 0; n < 4; ++n)
        acc[m][n] = __builtin_amdgcn_mfma_f32_16x16x32_bf16(afQ[m], bqQ[n], acc[m][n], 0, 0, 0);
    __builtin_amdgcn_s_setprio(0);
    // no barrier: {P4(t), P1(t+1)} reads d^1 only, stages d only
  }

  float sm0 = 0.f, sm1 = 0.f;
  if (MODE == 0) {
    float w0 = wmix[0], w1 = wmix[1];
    float mx = fmaxf(w0, w1);
    float e0 = expf(w0 - mx), e1 = expf(w1 - mx);
    float inv = 1.f / (e0 + e1);
    sm0 = e0 * inv;
    sm1 = e1 * inv;
  }
  float bc[4];
  int cs[4];
#pragma unroll
  for (int n = 0; n < 4; ++n) {
    int c = col0 + wc * 64 + n * 16 + l15;
    cs[n] = c;
    bc[n] = (MODE == 2 && c >= N) ? 0.f : (bias0[c] + (MODE == 0 ? bias1[c] : 0.f));
  }
#pragma unroll
  for (int m = 0; m < 8; ++m) {
#pragma unroll
    for (int n = 0; n < 4; ++n) {
      int c = cs[n];
      if (MODE == 2 && c >= N) continue;
      int r0 = row0 + wr * 128 + m * 16 + slot * 4;
#pragma unroll
      for (int r = 0; r < 4; ++r) {
        float v = acc[m][n][r] + bc[n];
        int rr = r0 + r;
        if (MODE == 0) {
          float x1v = fmaxf(v, 0.f);
          float x2v = bf2f(x2b[(size_t)rr * DD + c]);
          ((u16*)Cout)[(size_t)rr * ldc + c] = f2bf(sm0 * x1v + sm1 * x2v);
        } else if (MODE == 1) {
          ((u16*)Cout)[(size_t)rr * ldc + c] = f2bf(fmaxf(v, 0.f));
        } else {
          ((float*)Cout)[(size_t)rr * ldc + c] = v;
        }
      }
    }
  }
}

extern "C" void kernel_launch(void* const* d_in, const int* in_sizes, int n_in,
                              void* d_out, int out_size, void* d_ws, size_t ws_size,
                              hipStream_t stream) {
  const float* esm   = (const float*)d_in[0];
  const float* ipw   = (const float*)d_in[1];
  const float* Wesm  = (const float*)d_in[2];
  const float* besm  = (const float*)d_in[3];
  const float* bias1 = (const float*)d_in[4];
  const float* bias2 = (const float*)d_in[5];
  const float* wmix  = (const float*)d_in[6];
  const float* Wupd  = (const float*)d_in[7];
  const float* bupd  = (const float*)d_in[8];
  const float* Wout  = (const float*)d_in[9];
  const float* bout  = (const float*)d_in[10];
  const float* selfw = (const float*)d_in[11];
  const float* ppiw  = (const float*)d_in[12];
  const int* inputs  = (const int*)d_in[13];
  const int* ipidx   = (const int*)d_in[14];
  const int* ipoff   = (const int*)d_in[15];
  const int* src     = (const int*)d_in[16];
  const int* dst     = (const int*)d_in[17];
  const int* tgt     = (const int*)d_in[18];
  float* out = (float*)d_out;

  char* ws = (char*)d_ws;
  size_t o = 0;
  auto take = [&](size_t b) {
    char* r = ws + o;
    o += (b + 255) & ~(size_t)255;
    return r;
  };
  u16* Wesm_b = (u16*)take(1024ull * 1280 * 2);
  u16* Wupd_b = (u16*)take(2ull * 1024 * 2048 * 2);
  u16* Wout_b = (u16*)take(5000ull * 2304 * 2);
  int* counts  = (int*)take((size_t)NN * 4);
  int* row_off = (int*)take((size_t)(NN + 1) * 4);
  int* cursor  = (int*)take((size_t)NN * 4);
  int4* rec    = (int4*)take((size_t)EE * 16);
  u16* h_b     = (u16*)take((size_t)NN * DD * 2);
  char* shared0 = ws + o;
  size_t x2_b = ((size_t)NN * DD * 2 + 255) & ~(size_t)255;
  size_t a1_b = ((size_t)NN * DESM * 2 + 255) & ~(size_t)255;
  u16* x2b    = (u16*)shared0;
  u16* A1     = (u16*)(shared0 + x2_b);
  u16* ipw_b  = (u16*)(shared0 + x2_b + a1_b);
  u16* cat_b  = (u16*)shared0;
  u16* A_last = (u16*)(shared0 + x2_b + a1_b);

  // ---- weight casts to bf16 (2D grid, no per-element div) ----
  cast_rows_k<<<dim3(3, 1024), 64, 0, stream>>>(Wesm, 1280, nullptr, Wesm_b, 1280, 0, 160);
  cast_rows_k<<<dim3(4, 2048), 64, 0, stream>>>(Wupd, 2048, nullptr, Wupd_b, 2048, 0, 256);
  cast_rows_k<<<dim3(5, 5000), 64, 0, stream>>>(Wout, 2304, nullptr, Wout_b, 2304, 0, 288);
  cast_rows_k<<<dim3(2, IPN), 64, 0, stream>>>(ipw, 1024, nullptr, ipw_b, 1024, 0, 128);

  // ---- x2 = relu(bag + bias2) as bf16 ----
  embed_bag_k<<<NN / 2, 256, 0, stream>>>(ipw_b, ipidx, ipoff, bias2, x2b);

  // ---- gather ESM rows for x1 GEMM ----
  cast_rows_k<<<dim3(3, NN), 64, 0, stream>>>(esm, 1280, inputs, A1, 1280, 0, 160);

  // ---- CSR by dst with packed edge records ----
  hipMemsetAsync(counts, 0, (size_t)NN * 4, stream);
  hist_k<<<EE / 256, 256, 0, stream>>>(dst, counts);
  scan_k<<<1, 256, 0, stream>>>(counts, row_off);
  hipMemcpyAsync(cursor, row_off, (size_t)NN * 4, hipMemcpyDeviceToDevice, stream);
  scatter_k<<<EE / 256, 256, 0, stream>>>(dst, src, selfw, ppiw, cursor, rec);

  // ---- x1 GEMM fused with softmax-mix of x2 -> h (bf16) ----
  gemm8_k<0><<<dim3(4, 64), 512, 0, stream>>>(A1, Wesm_b, NN, 1024, 1280, h_b, 1024,
                                              besm, bias1, x2b, wmix);

  // ---- ESM gather for the final concat ----
  cast_rows_k<<<dim3(3, NN), 64, 0, stream>>>(esm, 1280, tgt, A_last, 2304, 1024, 160);

  // ---- GCN layer 0 ----
  aggregate_k<<<NN / 2, 256, 0, stream>>>(h_b, row_off, rec, cat_b);
  gemm8_k<1><<<dim3(4, 64), 512, 0, stream>>>(cat_b, Wupd_b, NN, 1024, 2048, h_b, 1024,
                                              bupd, nullptr, nullptr, nullptr);

  // ---- GCN layer 1 ----
  aggregate_k<<<NN / 2, 256, 0, stream>>>(h_b, row_off, rec, cat_b);
  gemm8_k<1><<<dim3(4, 64), 512, 0, stream>>>(cat_b, Wupd_b + (size_t)1024 * 2048, NN, 1024,
                                              2048, A_last, 2304, bupd + 1024, nullptr,
                                              nullptr, nullptr);

  // ---- final output GEMM [16384,2304] x [5000,2304]^T ----
  gemm8_k<2><<<dim3(20, 64), 512, 0, stream>>>(A_last, Wout_b, NN, 5000, 2304, out, 5000,
                                               bout, nullptr, nullptr, nullptr);
}